// Round 4
// baseline (284.594 us; speedup 1.0000x reference)
//
#include <hip/hip_runtime.h>
#include <cstdint>
#include <cstddef>

// CrossAttention: B=4,S=2048,D=512,H=8,Dh=64. fp32 in/out, bf16 MFMA compute.
// R4: flash: 2 LDS buffers (32KB) + launch_bounds(256,4) -> 4 blocks/CU (was 2),
//     1 barrier/tile, epilogue blob split in 2 phases to fit 32KB.
//     cvt_x + prep_w merged into one `prep` kernel. gemms unchanged.

typedef __bf16 bf16;
typedef __bf16 bf16x4_t __attribute__((ext_vector_type(4)));
typedef __bf16 bf16x8_t __attribute__((ext_vector_type(8)));
typedef float  floatx4  __attribute__((ext_vector_type(4)));
typedef short  shortx4  __attribute__((ext_vector_type(4)));
typedef uint32_t u32x4  __attribute__((ext_vector_type(4)));

#define NB   4
#define SEQ  2048
#define DM   512
#define NH   8
#define DH   64
#define MTOT (NB * SEQ)   // 8192

// ws layout: Xb@0 (8MB) | Wqkvt@8388608 (1.5MB) | Wot@9961472 (0.5MB) | Qh@10485760 (8MB)
// Kh@18874368 (8MB) | Vt@27262976 (8MB) | Ob@35651584 (8MB)

__device__ __forceinline__ void gload16(const void* g, void* l) {
    __builtin_amdgcn_global_load_lds((const __attribute__((address_space(1))) unsigned int*)g,
                                     (__attribute__((address_space(3))) unsigned int*)l,
                                     16, 0, 0);
}

__device__ __forceinline__ shortx4 pack4(floatx4 v) {
    union { bf16x4_t h; shortx4 s; } u;
    u.h = (bf16x4_t){ (bf16)v[0], (bf16)v[1], (bf16)v[2], (bf16)v[3] };
    return u.s;
}

// Fused: blocks [0,4096) convert X fp32->bf16; blocks [4096,4352) transpose weights.
__global__ __launch_bounds__(256) void prep(
        const float* __restrict__ X, const float* __restrict__ Wq, const float* __restrict__ Wk,
        const float* __restrict__ Wv, const float* __restrict__ Wo,
        bf16* __restrict__ xb, bf16* __restrict__ Wqkvt, bf16* __restrict__ Wot) {
    __shared__ float T[64][65];
    const int tid = threadIdx.x;
    const int bx = blockIdx.x;
    if (bx < 4096) {
        int i = (bx * 256 + tid) * 4;
        float4 v = *(const float4*)(X + i);
        bf16x4_t o = { (bf16)v.x, (bf16)v.y, (bf16)v.z, (bf16)v.w };
        *(bf16x4_t*)(xb + i) = o;
        return;
    }
    const int idx = bx - 4096;
    const int m = idx >> 6;
    const int k0 = ((idx >> 3) & 7) * 64, n0 = (idx & 7) * 64;
    const float* W = (m == 0) ? Wq : (m == 1) ? Wk : (m == 2) ? Wv : Wo;
    const float scale = (m == 0) ? 0.18033688011112042f : 1.0f;  // 0.125 * log2(e)
#pragma unroll
    for (int p = 0; p < 4; p++) {
        int row = p * 16 + (tid >> 4), col = (tid & 15) * 4;
        float4 v = *(const float4*)(W + (size_t)(k0 + row) * DM + n0 + col);
        T[row][col + 0] = v.x * scale; T[row][col + 1] = v.y * scale;
        T[row][col + 2] = v.z * scale; T[row][col + 3] = v.w * scale;
    }
    __syncthreads();
#pragma unroll
    for (int p = 0; p < 4; p++) {
        int nr = p * 16 + (tid >> 4), kc = (tid & 15) * 4;
        bf16x4_t o = { (bf16)T[kc][nr], (bf16)T[kc + 1][nr], (bf16)T[kc + 2][nr], (bf16)T[kc + 3][nr] };
        bf16* dst = (m < 3) ? (Wqkvt + ((size_t)(m * DM + n0 + nr)) * DM + k0 + kc)
                            : (Wot + (size_t)(n0 + nr) * DM + k0 + kc);
        *(bf16x4_t*)dst = o;
    }
}

// QKV gemm: C = Xb[8192x512] * Wqkvt[1536x512]^T, 128x128 tiles. Epilogue re-tiles through
// LDS and stores coalesced b128 to per-head Qh/Kh (row-major) and Vt (transposed).
__global__ __launch_bounds__(256) void gemm_qkv(
        const bf16* __restrict__ A, const bf16* __restrict__ Bt,
        bf16* __restrict__ Qh, bf16* __restrict__ Kh, bf16* __restrict__ Vt) {
    __shared__ __attribute__((aligned(16))) bf16 Sm[2][128 * 64];
    bf16* As = Sm[0]; bf16* Bs = Sm[1];
    const int tid = threadIdx.x;
    const int wave = tid >> 6, lane = tid & 63;
    const int l15 = lane & 15, quad = lane >> 4, h7 = l15 & 7;
    const int m0 = blockIdx.x * 128, n0 = blockIdx.y * 128;
    const int mw = (wave >> 1) * 64, nw = (wave & 1) * 64;
    const int srow = lane >> 3, sc = (lane & 7) ^ srow;

    floatx4 zero = {0.f, 0.f, 0.f, 0.f};
    floatx4 acc[4][4];
#pragma unroll
    for (int i = 0; i < 4; i++)
#pragma unroll
        for (int j = 0; j < 4; j++) acc[i][j] = zero;

    for (int k0 = 0; k0 < DM; k0 += 64) {
#pragma unroll
        for (int t = 0; t < 4; t++) {
            int row = wave * 32 + t * 8 + srow;
            gload16(A  + (size_t)(m0 + row) * DM + k0 + sc * 8, As + (wave * 32 + t * 8) * 64);
            gload16(Bt + (size_t)(n0 + row) * DM + k0 + sc * 8, Bs + (wave * 32 + t * 8) * 64);
        }
        __syncthreads();
#pragma unroll
        for (int ks = 0; ks < 2; ks++) {
            bf16x8_t af[4], bfr[4];
#pragma unroll
            for (int i = 0; i < 4; i++)
                af[i] = *(const bf16x8_t*)(As + (mw + i * 16 + l15) * 64 + (((ks * 4 + quad) ^ h7) * 8));
#pragma unroll
            for (int j = 0; j < 4; j++)
                bfr[j] = *(const bf16x8_t*)(Bs + (nw + j * 16 + l15) * 64 + (((ks * 4 + quad) ^ h7) * 8));
#pragma unroll
            for (int i = 0; i < 4; i++)
#pragma unroll
                for (int j = 0; j < 4; j++)
                    acc[i][j] = __builtin_amdgcn_mfma_f32_16x16x32_bf16(af[i], bfr[j], acc[i][j], 0, 0, 0);
        }
        __syncthreads();
    }

    // Epilogue via LDS re-tile
    bf16* E = (bf16*)Sm;
    const int sect = n0 >> 9;   // 0:Q 1:K 2:V
    const int bq = m0 >> 11;
    if (sect != 2) {
        bf16* dstbase = (sect == 0) ? Qh : Kh;
#pragma unroll
        for (int p = 0; p < 2; p++) {   // m-half
            if ((wave >> 1) == p) {
#pragma unroll
                for (int i = 0; i < 4; i++)
#pragma unroll
                    for (int j = 0; j < 4; j++)
#pragma unroll
                        for (int r = 0; r < 4; r++)
                            E[(i * 16 + quad * 4 + r) * 136 + nw + j * 16 + l15] = (bf16)acc[i][j][r];
            }
            __syncthreads();
#pragma unroll
            for (int pp = 0; pp < 4; pp++) {
                int idx = pp * 256 + tid;
                int rowl = idx >> 4, chunk = idx & 15;
                u32x4 v = *(const u32x4*)(E + rowl * 136 + chunk * 8);
                int mm = m0 + p * 64 + rowl;
                int s = mm & (SEQ - 1);
                int n = n0 + chunk * 8;
                int h = (n >> 6) & 7, d = n & 63;
                *(u32x4*)(dstbase + (((size_t)(bq * NH + h)) * SEQ + s) * DH + d) = v;
            }
            __syncthreads();
        }
    } else {
        // V: transpose in LDS ([n][m]) then store s-contiguous to Vt[bh][d][s]
#pragma unroll
        for (int p = 0; p < 2; p++) {   // n-half
            if ((wave & 1) == p) {
#pragma unroll
                for (int i = 0; i < 4; i++)
#pragma unroll
                    for (int j = 0; j < 4; j++)
                        *(shortx4*)(E + (j * 16 + l15) * 136 + mw + i * 16 + quad * 4) = pack4(acc[i][j]);
            }
            __syncthreads();
#pragma unroll
            for (int pp = 0; pp < 4; pp++) {
                int idx = pp * 256 + tid;
                int rowl = idx >> 4, chunk = idx & 15;
                u32x4 v = *(const u32x4*)(E + rowl * 136 + chunk * 8);
                int n = n0 + p * 64 + rowl;
                int h = (n >> 6) & 7, d = n & 63;
                int s = (m0 & (SEQ - 1)) + chunk * 8;
                *(u32x4*)(Vt + (((size_t)(bq * NH + h)) * DH + d) * SEQ + s) = v;
            }
            __syncthreads();
        }
    }
}

// Out projection: C = Ob[8192x512] * Wot[512x512]^T + bo, 64x128 tiles, grid 512.
__global__ __launch_bounds__(256) void gemm_out(
        const bf16* __restrict__ A, const bf16* __restrict__ Bt,
        const float* __restrict__ bo, float* __restrict__ out) {
    __shared__ __attribute__((aligned(16))) bf16 As[64 * 64];
    __shared__ __attribute__((aligned(16))) bf16 Bs[128 * 64];
    const int tid = threadIdx.x;
    const int wave = tid >> 6, lane = tid & 63;
    const int l15 = lane & 15, quad = lane >> 4, h7 = l15 & 7;
    const int m0 = blockIdx.x * 64, n0 = blockIdx.y * 128;
    const int nw = wave * 32;
    const int srow = lane >> 3, sc = (lane & 7) ^ srow;

    floatx4 zero = {0.f, 0.f, 0.f, 0.f};
    floatx4 acc[4][2];
#pragma unroll
    for (int i = 0; i < 4; i++)
#pragma unroll
        for (int j = 0; j < 2; j++) acc[i][j] = zero;

    for (int k0 = 0; k0 < DM; k0 += 64) {
#pragma unroll
        for (int t = 0; t < 2; t++) {
            int row = wave * 16 + t * 8 + srow;
            gload16(A + (size_t)(m0 + row) * DM + k0 + sc * 8, As + (wave * 16 + t * 8) * 64);
        }
#pragma unroll
        for (int t = 0; t < 4; t++) {
            int row = wave * 32 + t * 8 + srow;
            gload16(Bt + (size_t)(n0 + row) * DM + k0 + sc * 8, Bs + (wave * 32 + t * 8) * 64);
        }
        __syncthreads();
#pragma unroll
        for (int ks = 0; ks < 2; ks++) {
            bf16x8_t af[4], bfr[2];
#pragma unroll
            for (int i = 0; i < 4; i++)
                af[i] = *(const bf16x8_t*)(As + (i * 16 + l15) * 64 + (((ks * 4 + quad) ^ h7) * 8));
#pragma unroll
            for (int j = 0; j < 2; j++)
                bfr[j] = *(const bf16x8_t*)(Bs + (nw + j * 16 + l15) * 64 + (((ks * 4 + quad) ^ h7) * 8));
#pragma unroll
            for (int i = 0; i < 4; i++)
#pragma unroll
                for (int j = 0; j < 2; j++)
                    acc[i][j] = __builtin_amdgcn_mfma_f32_16x16x32_bf16(af[i], bfr[j], acc[i][j], 0, 0, 0);
        }
        __syncthreads();
    }
#pragma unroll
    for (int i = 0; i < 4; i++)
#pragma unroll
        for (int j = 0; j < 2; j++)
#pragma unroll
            for (int r = 0; r < 4; r++) {
                int m = m0 + i * 16 + quad * 4 + r;
                int n = n0 + nw + j * 16 + l15;
                out[(size_t)m * DM + n] = acc[i][j][r] + bo[n];
            }
}

// Flash attention, S^T orientation, kv-split waves, 2 buffers, 1 barrier/tile, 4 blocks/CU.
// Block: 4 waves = 2 q-halves(64q) x 2 kv-halves(32kv). Grid 512 (32 bh x 16 qtiles).
__global__ __launch_bounds__(256, 4) void flash_attn(
        const bf16* __restrict__ Q, const bf16* __restrict__ Kh,
        const bf16* __restrict__ Vt, bf16* __restrict__ Ob) {
    __shared__ __attribute__((aligned(16))) bf16 SMEM[2 * 8192];   // 2 bufs x (K 4096 | V 4096) = 32KB
    const int tid = threadIdx.x;
    const int wave = tid >> 6, lane = tid & 63;
    const int l15 = lane & 15, quad = lane >> 4, h7 = l15 & 7;
    const int qh = wave >> 1, kvh = wave & 1;
    const int qt = blockIdx.x & 15, bh = blockIdx.x >> 4;
    const int q0 = qt * 128;
    const bf16* Kb = Kh + (size_t)bh * SEQ * DH;
    const bf16* Vb = Vt + (size_t)bh * DH * SEQ;

    // Q fragments: B-operand [n=q][k=d], 4 subtiles of 16 q each (64 q per wave)
    bf16x8_t aq[4][2];
#pragma unroll
    for (int sub = 0; sub < 4; sub++) {
        const bf16* qr = Q + ((size_t)bh * SEQ + q0 + qh * 64 + sub * 16 + l15) * DH;
        aq[sub][0] = *(const bf16x8_t*)(qr + quad * 8);
        aq[sub][1] = *(const bf16x8_t*)(qr + 32 + quad * 8);
    }

    const int srow = lane >> 3, sc = (lane & 7) ^ srow;
    auto stage = [&](int buf, int kv0) {
#pragma unroll
        for (int t = 0; t < 2; t++) {
            int rb = wave * 16 + t * 8;
            gload16(Kb + (size_t)(kv0 + rb + srow) * DH + sc * 8, SMEM + buf * 8192 + rb * 64);
            gload16(Vb + (size_t)(rb + srow) * SEQ + kv0 + sc * 8, SMEM + buf * 8192 + 4096 + rb * 64);
        }
    };

    floatx4 zero = {0.f, 0.f, 0.f, 0.f};
    floatx4 oacc[4][4];
    float l_run[4] = {0.f, 0.f, 0.f, 0.f};
#pragma unroll
    for (int sub = 0; sub < 4; sub++)
#pragma unroll
        for (int d = 0; d < 4; d++) oacc[sub][d] = zero;

    stage(0, 0);
    for (int it = 0; it < SEQ / 64; it++) {
        __syncthreads();                       // drains stage(it); all waves past compute(it-1)
        if (it + 1 < SEQ / 64) stage((it + 1) & 1, (it + 1) * 64);
        const bf16* Ks = SMEM + (it & 1) * 8192;
        const bf16* Vs = Ks + 4096;

        floatx4 st[4][2];
#pragma unroll
        for (int nsl = 0; nsl < 2; nsl++) {
            int row = (kvh * 2 + nsl) * 16 + l15;
            const bf16* kr = Ks + row * 64;
            bf16x8_t k0 = *(const bf16x8_t*)(kr + ((quad ^ h7) * 8));
            bf16x8_t k1 = *(const bf16x8_t*)(kr + (((4 + quad) ^ h7) * 8));
#pragma unroll
            for (int sub = 0; sub < 4; sub++) {
                floatx4 a = zero;
                a = __builtin_amdgcn_mfma_f32_16x16x32_bf16(k0, aq[sub][0], a, 0, 0, 0);
                a = __builtin_amdgcn_mfma_f32_16x16x32_bf16(k1, aq[sub][1], a, 0, 0, 0);
                st[sub][nsl] = a;
            }
        }
#pragma unroll
        for (int sub = 0; sub < 4; sub++) {
            float s = 0.f;
#pragma unroll
            for (int nsl = 0; nsl < 2; nsl++)
#pragma unroll
                for (int r = 0; r < 4; r++) {
                    float p = __builtin_amdgcn_exp2f(st[sub][nsl][r]);
                    st[sub][nsl][r] = p;
                    s += p;
                }
            l_run[sub] += s;
        }
#pragma unroll
        for (int cl = 0; cl < 2; cl++) {
            int c = kvh * 2 + cl;
            shortx4 ap[4];
#pragma unroll
            for (int sub = 0; sub < 4; sub++) ap[sub] = pack4(st[sub][cl]);
            int cc = 2 * c + (quad >> 1);
#pragma unroll
            for (int d = 0; d < 4; d++) {
                const bf16* vr = Vs + (d * 16 + l15) * 64;
                shortx4 bv = *(const shortx4*)(vr + ((cc ^ h7) * 8) + (quad & 1) * 4);
#pragma unroll
                for (int sub = 0; sub < 4; sub++)
                    oacc[sub][d] = __builtin_amdgcn_mfma_f32_16x16x16bf16_1k(ap[sub], bv, oacc[sub][d], 0, 0, 0);
            }
        }
    }

    // reduce l across quads (q = l15), then combine kv-halves via LDS blob, 2 phases
    float lf[4];
#pragma unroll
    for (int sub = 0; sub < 4; sub++) {
        float l = l_run[sub];
        l += __shfl_xor(l, 16, 64);
        l += __shfl_xor(l, 32, 64);
        lf[sub] = l;
    }
    const int b = bh >> 3, h = bh & 7;
    float* blob = (float*)SMEM;   // per q-half: 34 rows x 64 floats (8.7KB), x2 halves
    __syncthreads();
#pragma unroll
    for (int ph = 0; ph < 2; ph++) {
        if (kvh == 1) {
#pragma unroll
            for (int sl = 0; sl < 2; sl++) {
                int sub = ph * 2 + sl;
#pragma unroll
                for (int d = 0; d < 4; d++)
#pragma unroll
                    for (int r = 0; r < 4; r++)
                        blob[qh * 2176 + ((sl * 4 + d) * 4 + r) * 64 + lane] = oacc[sub][d][r];
                blob[qh * 2176 + (32 + sl) * 64 + lane] = lf[sub];
            }
        }
        __syncthreads();
        if (kvh == 0) {
#pragma unroll
            for (int sl = 0; sl < 2; sl++) {
                int sub = ph * 2 + sl;
                float lt = lf[sub] + blob[qh * 2176 + (32 + sl) * 64 + lane];
                float linv[4];
#pragma unroll
                for (int r = 0; r < 4; r++) linv[r] = 1.0f / __shfl(lt, quad * 4 + r, 64);
#pragma unroll
                for (int d = 0; d < 4; d++)
#pragma unroll
                    for (int r = 0; r < 4; r++) {
                        float o = oacc[sub][d][r] + blob[qh * 2176 + ((sl * 4 + d) * 4 + r) * 64 + lane];
                        int s = q0 + qh * 64 + sub * 16 + quad * 4 + r;
                        Ob[((size_t)b * SEQ + s) * DM + h * DH + d * 16 + l15] = (bf16)(o * linv[r]);
                    }
            }
        }
        __syncthreads();
    }
}

extern "C" void kernel_launch(void* const* d_in, const int* in_sizes, int n_in,
                              void* d_out, int out_size, void* d_ws, size_t ws_size,
                              hipStream_t stream) {
    const float* X  = (const float*)d_in[0];
    const float* Wq = (const float*)d_in[1];
    const float* Wk = (const float*)d_in[2];
    const float* Wv = (const float*)d_in[3];
    const float* Wo = (const float*)d_in[4];
    const float* bo = (const float*)d_in[5];
    float* out = (float*)d_out;

    char* ws = (char*)d_ws;
    bf16* Xb    = (bf16*)(ws + 0);
    bf16* Wqkvt = (bf16*)(ws + 8388608);
    bf16* Wot   = (bf16*)(ws + 9961472);
    bf16* Qh    = (bf16*)(ws + 10485760);
    bf16* Kh    = (bf16*)(ws + 18874368);
    bf16* Vt    = (bf16*)(ws + 27262976);
    bf16* Ob    = (bf16*)(ws + 35651584);

    prep<<<4096 + 256, 256, 0, stream>>>(X, Wq, Wk, Wv, Wo, Xb, Wqkvt, Wot);
    gemm_qkv<<<dim3(MTOT / 128, 1536 / 128), 256, 0, stream>>>(Xb, Wqkvt, Qh, Kh, Vt);
    flash_attn<<<NB * NH * (SEQ / 128), 256, 0, stream>>>(Qh, Kh, Vt, Ob);
    gemm_out<<<dim3(MTOT / 64, DM / 128), 256, 0, stream>>>(Ob, Wot, bo, out);
}

// Round 7
// 159.271 us; speedup vs baseline: 1.7869x; 1.7869x over previous
//
#include <hip/hip_runtime.h>
#include <cstdint>
#include <cstddef>

// CrossAttention: B=4,S=2048,D=512,H=8,Dh=64. fp32 in/out, bf16 MFMA compute.
// R7: consolidation. flash = R3's exact passing kernel (4-buffer unroll-2, (256,2),
//     51.7us measured). prep = R4's merged cvt+transpose (passed). gemms = proven.
//     R5/R6 q-tile-64 rewrites both failed correctness and are abandoned.

typedef __bf16 bf16;
typedef __bf16 bf16x4_t __attribute__((ext_vector_type(4)));
typedef __bf16 bf16x8_t __attribute__((ext_vector_type(8)));
typedef float  floatx4  __attribute__((ext_vector_type(4)));
typedef short  shortx4  __attribute__((ext_vector_type(4)));
typedef uint32_t u32x4  __attribute__((ext_vector_type(4)));

#define NB   4
#define SEQ  2048
#define DM   512
#define NH   8
#define DH   64
#define MTOT (NB * SEQ)   // 8192

// ws layout: Xb@0 (8MB) | Wqkvt@8388608 (1.5MB) | Wot@9961472 (0.5MB) | Qh@10485760 (8MB)
// Kh@18874368 (8MB) | Vt@27262976 (8MB) | Ob@35651584 (8MB)

__device__ __forceinline__ void gload16(const void* g, void* l) {
    __builtin_amdgcn_global_load_lds((const __attribute__((address_space(1))) unsigned int*)g,
                                     (__attribute__((address_space(3))) unsigned int*)l,
                                     16, 0, 0);
}

__device__ __forceinline__ shortx4 pack4(floatx4 v) {
    union { bf16x4_t h; shortx4 s; } u;
    u.h = (bf16x4_t){ (bf16)v[0], (bf16)v[1], (bf16)v[2], (bf16)v[3] };
    return u.s;
}

// Fused: blocks [0,4096) convert X fp32->bf16; blocks [4096,4352) transpose weights.
__global__ __launch_bounds__(256) void prep(
        const float* __restrict__ X, const float* __restrict__ Wq, const float* __restrict__ Wk,
        const float* __restrict__ Wv, const float* __restrict__ Wo,
        bf16* __restrict__ xb, bf16* __restrict__ Wqkvt, bf16* __restrict__ Wot) {
    __shared__ float T[64][65];
    const int tid = threadIdx.x;
    const int bx = blockIdx.x;
    if (bx < 4096) {
        int i = (bx * 256 + tid) * 4;
        float4 v = *(const float4*)(X + i);
        bf16x4_t o = { (bf16)v.x, (bf16)v.y, (bf16)v.z, (bf16)v.w };
        *(bf16x4_t*)(xb + i) = o;
        return;
    }
    const int idx = bx - 4096;
    const int m = idx >> 6;
    const int k0 = ((idx >> 3) & 7) * 64, n0 = (idx & 7) * 64;
    const float* W = (m == 0) ? Wq : (m == 1) ? Wk : (m == 2) ? Wv : Wo;
    const float scale = (m == 0) ? 0.18033688011112042f : 1.0f;  // 0.125 * log2(e)
#pragma unroll
    for (int p = 0; p < 4; p++) {
        int row = p * 16 + (tid >> 4), col = (tid & 15) * 4;
        float4 v = *(const float4*)(W + (size_t)(k0 + row) * DM + n0 + col);
        T[row][col + 0] = v.x * scale; T[row][col + 1] = v.y * scale;
        T[row][col + 2] = v.z * scale; T[row][col + 3] = v.w * scale;
    }
    __syncthreads();
#pragma unroll
    for (int p = 0; p < 4; p++) {
        int nr = p * 16 + (tid >> 4), kc = (tid & 15) * 4;
        bf16x4_t o = { (bf16)T[kc][nr], (bf16)T[kc + 1][nr], (bf16)T[kc + 2][nr], (bf16)T[kc + 3][nr] };
        bf16* dst = (m < 3) ? (Wqkvt + ((size_t)(m * DM + n0 + nr)) * DM + k0 + kc)
                            : (Wot + (size_t)(n0 + nr) * DM + k0 + kc);
        *(bf16x4_t*)dst = o;
    }
}

// QKV gemm: C = Xb[8192x512] * Wqkvt[1536x512]^T, 128x128 tiles. Epilogue re-tiles through
// LDS and stores coalesced b128 to per-head Qh/Kh (row-major) and Vt (transposed).
__global__ __launch_bounds__(256) void gemm_qkv(
        const bf16* __restrict__ A, const bf16* __restrict__ Bt,
        bf16* __restrict__ Qh, bf16* __restrict__ Kh, bf16* __restrict__ Vt) {
    __shared__ __attribute__((aligned(16))) bf16 Sm[2][128 * 64];
    bf16* As = Sm[0]; bf16* Bs = Sm[1];
    const int tid = threadIdx.x;
    const int wave = tid >> 6, lane = tid & 63;
    const int l15 = lane & 15, quad = lane >> 4, h7 = l15 & 7;
    const int m0 = blockIdx.x * 128, n0 = blockIdx.y * 128;
    const int mw = (wave >> 1) * 64, nw = (wave & 1) * 64;
    const int srow = lane >> 3, sc = (lane & 7) ^ srow;

    floatx4 zero = {0.f, 0.f, 0.f, 0.f};
    floatx4 acc[4][4];
#pragma unroll
    for (int i = 0; i < 4; i++)
#pragma unroll
        for (int j = 0; j < 4; j++) acc[i][j] = zero;

    for (int k0 = 0; k0 < DM; k0 += 64) {
#pragma unroll
        for (int t = 0; t < 4; t++) {
            int row = wave * 32 + t * 8 + srow;
            gload16(A  + (size_t)(m0 + row) * DM + k0 + sc * 8, As + (wave * 32 + t * 8) * 64);
            gload16(Bt + (size_t)(n0 + row) * DM + k0 + sc * 8, Bs + (wave * 32 + t * 8) * 64);
        }
        __syncthreads();
#pragma unroll
        for (int ks = 0; ks < 2; ks++) {
            bf16x8_t af[4], bfr[4];
#pragma unroll
            for (int i = 0; i < 4; i++)
                af[i] = *(const bf16x8_t*)(As + (mw + i * 16 + l15) * 64 + (((ks * 4 + quad) ^ h7) * 8));
#pragma unroll
            for (int j = 0; j < 4; j++)
                bfr[j] = *(const bf16x8_t*)(Bs + (nw + j * 16 + l15) * 64 + (((ks * 4 + quad) ^ h7) * 8));
#pragma unroll
            for (int i = 0; i < 4; i++)
#pragma unroll
                for (int j = 0; j < 4; j++)
                    acc[i][j] = __builtin_amdgcn_mfma_f32_16x16x32_bf16(af[i], bfr[j], acc[i][j], 0, 0, 0);
        }
        __syncthreads();
    }

    // Epilogue via LDS re-tile
    bf16* E = (bf16*)Sm;
    const int sect = n0 >> 9;   // 0:Q 1:K 2:V
    const int bq = m0 >> 11;
    if (sect != 2) {
        bf16* dstbase = (sect == 0) ? Qh : Kh;
#pragma unroll
        for (int p = 0; p < 2; p++) {   // m-half
            if ((wave >> 1) == p) {
#pragma unroll
                for (int i = 0; i < 4; i++)
#pragma unroll
                    for (int j = 0; j < 4; j++)
#pragma unroll
                        for (int r = 0; r < 4; r++)
                            E[(i * 16 + quad * 4 + r) * 136 + nw + j * 16 + l15] = (bf16)acc[i][j][r];
            }
            __syncthreads();
#pragma unroll
            for (int pp = 0; pp < 4; pp++) {
                int idx = pp * 256 + tid;
                int rowl = idx >> 4, chunk = idx & 15;
                u32x4 v = *(const u32x4*)(E + rowl * 136 + chunk * 8);
                int mm = m0 + p * 64 + rowl;
                int s = mm & (SEQ - 1);
                int n = n0 + chunk * 8;
                int h = (n >> 6) & 7, d = n & 63;
                *(u32x4*)(dstbase + (((size_t)(bq * NH + h)) * SEQ + s) * DH + d) = v;
            }
            __syncthreads();
        }
    } else {
        // V: transpose in LDS ([n][m]) then store s-contiguous to Vt[bh][d][s]
#pragma unroll
        for (int p = 0; p < 2; p++) {   // n-half
            if ((wave & 1) == p) {
#pragma unroll
                for (int i = 0; i < 4; i++)
#pragma unroll
                    for (int j = 0; j < 4; j++)
                        *(shortx4*)(E + (j * 16 + l15) * 136 + mw + i * 16 + quad * 4) = pack4(acc[i][j]);
            }
            __syncthreads();
#pragma unroll
            for (int pp = 0; pp < 4; pp++) {
                int idx = pp * 256 + tid;
                int rowl = idx >> 4, chunk = idx & 15;
                u32x4 v = *(const u32x4*)(E + rowl * 136 + chunk * 8);
                int n = n0 + p * 64 + rowl;
                int h = (n >> 6) & 7, d = n & 63;
                int s = (m0 & (SEQ - 1)) + chunk * 8;
                *(u32x4*)(Vt + (((size_t)(bq * NH + h)) * DH + d) * SEQ + s) = v;
            }
            __syncthreads();
        }
    }
}

// Out projection: C = Ob[8192x512] * Wot[512x512]^T + bo, 64x128 tiles, grid 512.
__global__ __launch_bounds__(256) void gemm_out(
        const bf16* __restrict__ A, const bf16* __restrict__ Bt,
        const float* __restrict__ bo, float* __restrict__ out) {
    __shared__ __attribute__((aligned(16))) bf16 As[64 * 64];
    __shared__ __attribute__((aligned(16))) bf16 Bs[128 * 64];
    const int tid = threadIdx.x;
    const int wave = tid >> 6, lane = tid & 63;
    const int l15 = lane & 15, quad = lane >> 4, h7 = l15 & 7;
    const int m0 = blockIdx.x * 64, n0 = blockIdx.y * 128;
    const int nw = wave * 32;
    const int srow = lane >> 3, sc = (lane & 7) ^ srow;

    floatx4 zero = {0.f, 0.f, 0.f, 0.f};
    floatx4 acc[4][2];
#pragma unroll
    for (int i = 0; i < 4; i++)
#pragma unroll
        for (int j = 0; j < 2; j++) acc[i][j] = zero;

    for (int k0 = 0; k0 < DM; k0 += 64) {
#pragma unroll
        for (int t = 0; t < 2; t++) {
            int row = wave * 16 + t * 8 + srow;
            gload16(A + (size_t)(m0 + row) * DM + k0 + sc * 8, As + (wave * 16 + t * 8) * 64);
        }
#pragma unroll
        for (int t = 0; t < 4; t++) {
            int row = wave * 32 + t * 8 + srow;
            gload16(Bt + (size_t)(n0 + row) * DM + k0 + sc * 8, Bs + (wave * 32 + t * 8) * 64);
        }
        __syncthreads();
#pragma unroll
        for (int ks = 0; ks < 2; ks++) {
            bf16x8_t af[4], bfr[2];
#pragma unroll
            for (int i = 0; i < 4; i++)
                af[i] = *(const bf16x8_t*)(As + (i * 16 + l15) * 64 + (((ks * 4 + quad) ^ h7) * 8));
#pragma unroll
            for (int j = 0; j < 2; j++)
                bfr[j] = *(const bf16x8_t*)(Bs + (nw + j * 16 + l15) * 64 + (((ks * 4 + quad) ^ h7) * 8));
#pragma unroll
            for (int i = 0; i < 4; i++)
#pragma unroll
                for (int j = 0; j < 2; j++)
                    acc[i][j] = __builtin_amdgcn_mfma_f32_16x16x32_bf16(af[i], bfr[j], acc[i][j], 0, 0, 0);
        }
        __syncthreads();
    }
#pragma unroll
    for (int i = 0; i < 4; i++)
#pragma unroll
        for (int j = 0; j < 2; j++)
#pragma unroll
            for (int r = 0; r < 4; r++) {
                int m = m0 + i * 16 + quad * 4 + r;
                int n = n0 + nw + j * 16 + l15;
                out[(size_t)m * DM + n] = acc[i][j][r] + bo[n];
            }
}

// Flash attention (R3's exact passing kernel): S^T orientation, kv-split waves,
// 4-buffer unroll-2. Block: 4 waves = 2 q-halves(64q) x 2 kv-halves(32kv).
// Grid 512 (32 bh x 16 qtiles of 128 q).
__global__ __launch_bounds__(256, 2) void flash_attn(
        const bf16* __restrict__ Q, const bf16* __restrict__ Kh,
        const bf16* __restrict__ Vt, bf16* __restrict__ Ob) {
    __shared__ __attribute__((aligned(16))) bf16 SMEM[4 * 8192];   // 4 bufs x (K 4096 | V 4096)
    const int tid = threadIdx.x;
    const int wave = tid >> 6, lane = tid & 63;
    const int l15 = lane & 15, quad = lane >> 4, h7 = l15 & 7;
    const int qh = wave >> 1, kvh = wave & 1;
    const int qt = blockIdx.x & 15, bh = blockIdx.x >> 4;
    const int q0 = qt * 128;
    const bf16* Kb = Kh + (size_t)bh * SEQ * DH;
    const bf16* Vb = Vt + (size_t)bh * DH * SEQ;

    // Q fragments: B-operand [n=q][k=d], 4 subtiles of 16 q each (64 q per wave)
    bf16x8_t aq[4][2];
#pragma unroll
    for (int sub = 0; sub < 4; sub++) {
        const bf16* qr = Q + ((size_t)bh * SEQ + q0 + qh * 64 + sub * 16 + l15) * DH;
        aq[sub][0] = *(const bf16x8_t*)(qr + quad * 8);
        aq[sub][1] = *(const bf16x8_t*)(qr + 32 + quad * 8);
    }

    const int srow = lane >> 3, sc = (lane & 7) ^ srow;
    auto stage = [&](int buf, int kv0) {
#pragma unroll
        for (int t = 0; t < 2; t++) {
            int rb = wave * 16 + t * 8;
            gload16(Kb + (size_t)(kv0 + rb + srow) * DH + sc * 8, SMEM + buf * 8192 + rb * 64);
            gload16(Vb + (size_t)(rb + srow) * SEQ + kv0 + sc * 8, SMEM + buf * 8192 + 4096 + rb * 64);
        }
    };

    floatx4 zero = {0.f, 0.f, 0.f, 0.f};
    floatx4 oacc[4][4];
    float l_run[4] = {0.f, 0.f, 0.f, 0.f};
#pragma unroll
    for (int sub = 0; sub < 4; sub++)
#pragma unroll
        for (int d = 0; d < 4; d++) oacc[sub][d] = zero;

    stage(0, 0);
    stage(1, 64);
    for (int seg = 0; seg < 16; seg++) {
        __syncthreads();
        if (seg < 15) {
            stage((2 * seg + 2) & 3, (2 * seg + 2) * 64);
            stage((2 * seg + 3) & 3, (2 * seg + 3) * 64);
        }
#pragma unroll
        for (int half = 0; half < 2; half++) {
            const bf16* Ks = SMEM + ((2 * seg + half) & 3) * 8192;
            const bf16* Vs = Ks + 4096;
            floatx4 st[4][2];
#pragma unroll
            for (int nsl = 0; nsl < 2; nsl++) {
                int row = (kvh * 2 + nsl) * 16 + l15;
                const bf16* kr = Ks + row * 64;
                bf16x8_t k0 = *(const bf16x8_t*)(kr + ((quad ^ h7) * 8));
                bf16x8_t k1 = *(const bf16x8_t*)(kr + (((4 + quad) ^ h7) * 8));
#pragma unroll
                for (int sub = 0; sub < 4; sub++) {
                    floatx4 a = zero;
                    a = __builtin_amdgcn_mfma_f32_16x16x32_bf16(k0, aq[sub][0], a, 0, 0, 0);
                    a = __builtin_amdgcn_mfma_f32_16x16x32_bf16(k1, aq[sub][1], a, 0, 0, 0);
                    st[sub][nsl] = a;
                }
            }
#pragma unroll
            for (int sub = 0; sub < 4; sub++) {
                float s = 0.f;
#pragma unroll
                for (int nsl = 0; nsl < 2; nsl++)
#pragma unroll
                    for (int r = 0; r < 4; r++) {
                        float p = __builtin_amdgcn_exp2f(st[sub][nsl][r]);
                        st[sub][nsl][r] = p;
                        s += p;
                    }
                l_run[sub] += s;
            }
#pragma unroll
            for (int cl = 0; cl < 2; cl++) {
                int c = kvh * 2 + cl;
                shortx4 ap[4];
#pragma unroll
                for (int sub = 0; sub < 4; sub++) ap[sub] = pack4(st[sub][cl]);
                int cc = 2 * c + (quad >> 1);
#pragma unroll
                for (int d = 0; d < 4; d++) {
                    const bf16* vr = Vs + (d * 16 + l15) * 64;
                    shortx4 bv = *(const shortx4*)(vr + ((cc ^ h7) * 8) + (quad & 1) * 4);
#pragma unroll
                    for (int sub = 0; sub < 4; sub++)
                        oacc[sub][d] = __builtin_amdgcn_mfma_f32_16x16x16bf16_1k(ap[sub], bv, oacc[sub][d], 0, 0, 0);
                }
            }
        }
    }

    // reduce l across quads (q = l15), then combine kv-halves via LDS blob
    float lf[4];
#pragma unroll
    for (int sub = 0; sub < 4; sub++) {
        float l = l_run[sub];
        l += __shfl_xor(l, 16, 64);
        l += __shfl_xor(l, 32, 64);
        lf[sub] = l;
    }
    __syncthreads();
    float* blob = (float*)SMEM + qh * (68 * 64);   // SoA [68][64] per q-half
    if (kvh == 1) {
#pragma unroll
        for (int sub = 0; sub < 4; sub++)
#pragma unroll
            for (int d = 0; d < 4; d++)
#pragma unroll
                for (int r = 0; r < 4; r++)
                    blob[((sub * 4 + d) * 4 + r) * 64 + lane] = oacc[sub][d][r];
#pragma unroll
        for (int sub = 0; sub < 4; sub++)
            blob[(64 + sub) * 64 + lane] = lf[sub];
    }
    __syncthreads();
    if (kvh == 0) {
#pragma unroll
        for (int sub = 0; sub < 4; sub++)
#pragma unroll
            for (int d = 0; d < 4; d++)
#pragma unroll
                for (int r = 0; r < 4; r++)
                    oacc[sub][d][r] += blob[((sub * 4 + d) * 4 + r) * 64 + lane];
#pragma unroll
        for (int sub = 0; sub < 4; sub++)
            lf[sub] += blob[(64 + sub) * 64 + lane];

        const int b = bh >> 3, h = bh & 7;
#pragma unroll
        for (int sub = 0; sub < 4; sub++) {
            float linv[4];
#pragma unroll
            for (int r = 0; r < 4; r++) linv[r] = 1.0f / __shfl(lf[sub], quad * 4 + r, 64);
#pragma unroll
            for (int d = 0; d < 4; d++)
#pragma unroll
                for (int r = 0; r < 4; r++) {
                    int s = q0 + qh * 64 + sub * 16 + quad * 4 + r;
                    Ob[((size_t)b * SEQ + s) * DM + h * DH + d * 16 + l15] = (bf16)(oacc[sub][d][r] * linv[r]);
                }
        }
    }
}

extern "C" void kernel_launch(void* const* d_in, const int* in_sizes, int n_in,
                              void* d_out, int out_size, void* d_ws, size_t ws_size,
                              hipStream_t stream) {
    const float* X  = (const float*)d_in[0];
    const float* Wq = (const float*)d_in[1];
    const float* Wk = (const float*)d_in[2];
    const float* Wv = (const float*)d_in[3];
    const float* Wo = (const float*)d_in[4];
    const float* bo = (const float*)d_in[5];
    float* out = (float*)d_out;

    char* ws = (char*)d_ws;
    bf16* Xb    = (bf16*)(ws + 0);
    bf16* Wqkvt = (bf16*)(ws + 8388608);
    bf16* Wot   = (bf16*)(ws + 9961472);
    bf16* Qh    = (bf16*)(ws + 10485760);
    bf16* Kh    = (bf16*)(ws + 18874368);
    bf16* Vt    = (bf16*)(ws + 27262976);
    bf16* Ob    = (bf16*)(ws + 35651584);

    prep<<<4096 + 256, 256, 0, stream>>>(X, Wq, Wk, Wv, Wo, Xb, Wqkvt, Wot);
    gemm_qkv<<<dim3(MTOT / 128, 1536 / 128), 256, 0, stream>>>(Xb, Wqkvt, Qh, Kh, Vt);
    flash_attn<<<NB * NH * (SEQ / 128), 256, 0, stream>>>(Qh, Kh, Vt, Ob);
    gemm_out<<<dim3(MTOT / 64, DM / 128), 256, 0, stream>>>(Ob, Wot, bo, out);
}

// Round 8
// 148.837 us; speedup vs baseline: 1.9121x; 1.0701x over previous
//
#include <hip/hip_runtime.h>
#include <cstdint>
#include <cstddef>

// CrossAttention: B=4,S=2048,D=512,H=8,Dh=64. fp32 in/out, bf16 MFMA compute.
// R8: gemms pipelined (stage tile k+1 BEFORE computing tile k, alternating buffer
//     pairs, 1 barrier/iter — the R4/R7-flash proven pattern) to cover global->LDS
//     latency that the old 2-barrier loop exposed every K-iter. gemm_qkv epilogue:
//     single-phase 128x136 LDS re-tile (2 barriers, was 4). flash/prep unchanged (R7).

typedef __bf16 bf16;
typedef __bf16 bf16x4_t __attribute__((ext_vector_type(4)));
typedef __bf16 bf16x8_t __attribute__((ext_vector_type(8)));
typedef float  floatx4  __attribute__((ext_vector_type(4)));
typedef short  shortx4  __attribute__((ext_vector_type(4)));
typedef uint32_t u32x4  __attribute__((ext_vector_type(4)));

#define NB   4
#define SEQ  2048
#define DM   512
#define NH   8
#define DH   64
#define MTOT (NB * SEQ)   // 8192

// ws layout: Xb@0 (8MB) | Wqkvt@8388608 (1.5MB) | Wot@9961472 (0.5MB) | Qh@10485760 (8MB)
// Kh@18874368 (8MB) | Vt@27262976 (8MB) | Ob@35651584 (8MB)

__device__ __forceinline__ void gload16(const void* g, void* l) {
    __builtin_amdgcn_global_load_lds((const __attribute__((address_space(1))) unsigned int*)g,
                                     (__attribute__((address_space(3))) unsigned int*)l,
                                     16, 0, 0);
}

__device__ __forceinline__ shortx4 pack4(floatx4 v) {
    union { bf16x4_t h; shortx4 s; } u;
    u.h = (bf16x4_t){ (bf16)v[0], (bf16)v[1], (bf16)v[2], (bf16)v[3] };
    return u.s;
}

// Fused: blocks [0,4096) convert X fp32->bf16; blocks [4096,4352) transpose weights.
__global__ __launch_bounds__(256) void prep(
        const float* __restrict__ X, const float* __restrict__ Wq, const float* __restrict__ Wk,
        const float* __restrict__ Wv, const float* __restrict__ Wo,
        bf16* __restrict__ xb, bf16* __restrict__ Wqkvt, bf16* __restrict__ Wot) {
    __shared__ float T[64][65];
    const int tid = threadIdx.x;
    const int bx = blockIdx.x;
    if (bx < 4096) {
        int i = (bx * 256 + tid) * 4;
        float4 v = *(const float4*)(X + i);
        bf16x4_t o = { (bf16)v.x, (bf16)v.y, (bf16)v.z, (bf16)v.w };
        *(bf16x4_t*)(xb + i) = o;
        return;
    }
    const int idx = bx - 4096;
    const int m = idx >> 6;
    const int k0 = ((idx >> 3) & 7) * 64, n0 = (idx & 7) * 64;
    const float* W = (m == 0) ? Wq : (m == 1) ? Wk : (m == 2) ? Wv : Wo;
    const float scale = (m == 0) ? 0.18033688011112042f : 1.0f;  // 0.125 * log2(e)
#pragma unroll
    for (int p = 0; p < 4; p++) {
        int row = p * 16 + (tid >> 4), col = (tid & 15) * 4;
        float4 v = *(const float4*)(W + (size_t)(k0 + row) * DM + n0 + col);
        T[row][col + 0] = v.x * scale; T[row][col + 1] = v.y * scale;
        T[row][col + 2] = v.z * scale; T[row][col + 3] = v.w * scale;
    }
    __syncthreads();
#pragma unroll
    for (int p = 0; p < 4; p++) {
        int nr = p * 16 + (tid >> 4), kc = (tid & 15) * 4;
        bf16x4_t o = { (bf16)T[kc][nr], (bf16)T[kc + 1][nr], (bf16)T[kc + 2][nr], (bf16)T[kc + 3][nr] };
        bf16* dst = (m < 3) ? (Wqkvt + ((size_t)(m * DM + n0 + nr)) * DM + k0 + kc)
                            : (Wot + (size_t)(n0 + nr) * DM + k0 + kc);
        *(bf16x4_t*)dst = o;
    }
}

// QKV gemm, pipelined: C = Xb[8192x512] * Wqkvt[1536x512]^T, 128x128 tiles, BK=64,
// 2 buffer-pairs (64KB), stage-ahead-1, 1 barrier/iter. Single-phase LDS epilogue.
__global__ __launch_bounds__(256) void gemm_qkv(
        const bf16* __restrict__ A, const bf16* __restrict__ Bt,
        bf16* __restrict__ Qh, bf16* __restrict__ Kh, bf16* __restrict__ Vt) {
    __shared__ __attribute__((aligned(16))) bf16 AB[2][2][128 * 64];  // [buf][0=A,1=B]
    const int tid = threadIdx.x;
    const int wave = tid >> 6, lane = tid & 63;
    const int l15 = lane & 15, quad = lane >> 4, h7 = l15 & 7;
    const int m0 = blockIdx.x * 128, n0 = blockIdx.y * 128;
    const int mw = (wave >> 1) * 64, nw = (wave & 1) * 64;
    const int srow = lane >> 3, sc = (lane & 7) ^ srow;

    auto stage = [&](int buf, int k0) {
#pragma unroll
        for (int t = 0; t < 4; t++) {
            int rb = wave * 32 + t * 8;
            gload16(A  + (size_t)(m0 + rb + srow) * DM + k0 + sc * 8, AB[buf][0] + rb * 64);
            gload16(Bt + (size_t)(n0 + rb + srow) * DM + k0 + sc * 8, AB[buf][1] + rb * 64);
        }
    };

    floatx4 zero = {0.f, 0.f, 0.f, 0.f};
    floatx4 acc[4][4];
#pragma unroll
    for (int i = 0; i < 4; i++)
#pragma unroll
        for (int j = 0; j < 4; j++) acc[i][j] = zero;

    stage(0, 0);
    for (int kt = 0; kt < DM / 64; kt++) {
        __syncthreads();                       // drains stage(kt); all waves past compute(kt-1)
        if (kt + 1 < DM / 64) stage((kt + 1) & 1, (kt + 1) * 64);
        const bf16* As = AB[kt & 1][0];
        const bf16* Bs = AB[kt & 1][1];
#pragma unroll
        for (int ks = 0; ks < 2; ks++) {
            bf16x8_t af[4], bfr[4];
#pragma unroll
            for (int i = 0; i < 4; i++)
                af[i] = *(const bf16x8_t*)(As + (mw + i * 16 + l15) * 64 + (((ks * 4 + quad) ^ h7) * 8));
#pragma unroll
            for (int j = 0; j < 4; j++)
                bfr[j] = *(const bf16x8_t*)(Bs + (nw + j * 16 + l15) * 64 + (((ks * 4 + quad) ^ h7) * 8));
#pragma unroll
            for (int i = 0; i < 4; i++)
#pragma unroll
                for (int j = 0; j < 4; j++)
                    acc[i][j] = __builtin_amdgcn_mfma_f32_16x16x32_bf16(af[i], bfr[j], acc[i][j], 0, 0, 0);
        }
    }

    // Epilogue: single-phase 128x136 re-tile in the (now free) staging LDS (34.8KB <= 64KB)
    bf16* E = (bf16*)AB;
    const int sect = n0 >> 9;   // 0:Q 1:K 2:V
    const int bq = m0 >> 11;
    __syncthreads();            // all compute done before overwriting staging LDS
    if (sect != 2) {
        bf16* dstbase = (sect == 0) ? Qh : Kh;
#pragma unroll
        for (int i = 0; i < 4; i++)
#pragma unroll
            for (int j = 0; j < 4; j++)
#pragma unroll
                for (int r = 0; r < 4; r++)
                    E[(mw + i * 16 + quad * 4 + r) * 136 + nw + j * 16 + l15] = (bf16)acc[i][j][r];
        __syncthreads();
#pragma unroll
        for (int pp = 0; pp < 8; pp++) {
            int idx = pp * 256 + tid;          // 0..2047 : 128 rows x 16 chunks
            int rowl = idx >> 4, chunk = idx & 15;
            u32x4 v = *(const u32x4*)(E + rowl * 136 + chunk * 8);
            int s = (m0 + rowl) & (SEQ - 1);
            int n = n0 + chunk * 8;
            int h = (n >> 6) & 7, d = n & 63;
            *(u32x4*)(dstbase + (((size_t)(bq * NH + h)) * SEQ + s) * DH + d) = v;
        }
    } else {
        // V: transpose in LDS ([n][m]) then store s-contiguous to Vt[bh][d][s]
#pragma unroll
        for (int i = 0; i < 4; i++)
#pragma unroll
            for (int j = 0; j < 4; j++)
                *(shortx4*)(E + (nw + j * 16 + l15) * 136 + mw + i * 16 + quad * 4) = pack4(acc[i][j]);
        __syncthreads();
#pragma unroll
        for (int pp = 0; pp < 8; pp++) {
            int idx = pp * 256 + tid;          // 128 n-rows x 16 m-chunks
            int rowl = idx >> 4, chunk = idx & 15;
            u32x4 v = *(const u32x4*)(E + rowl * 136 + chunk * 8);
            int n = n0 + rowl;
            int h = (n >> 6) & 7, d = n & 63;
            int s = (m0 & (SEQ - 1)) + chunk * 8;
            *(u32x4*)(Vt + (((size_t)(bq * NH + h)) * DH + d) * SEQ + s) = v;
        }
    }
}

// Out projection, pipelined: C = Ob[8192x512] * Wot[512x512]^T + bo, 64x128 tiles,
// 2 buffer-pairs (48KB), stage-ahead-1, 1 barrier/iter. Grid 512.
__global__ __launch_bounds__(256) void gemm_out(
        const bf16* __restrict__ A, const bf16* __restrict__ Bt,
        const float* __restrict__ bo, float* __restrict__ out) {
    __shared__ __attribute__((aligned(16))) bf16 Ao[2][64 * 64];
    __shared__ __attribute__((aligned(16))) bf16 Bo[2][128 * 64];
    const int tid = threadIdx.x;
    const int wave = tid >> 6, lane = tid & 63;
    const int l15 = lane & 15, quad = lane >> 4, h7 = l15 & 7;
    const int m0 = blockIdx.x * 64, n0 = blockIdx.y * 128;
    const int nw = wave * 32;
    const int srow = lane >> 3, sc = (lane & 7) ^ srow;

    auto stage = [&](int buf, int k0) {
#pragma unroll
        for (int t = 0; t < 2; t++) {
            int rb = wave * 16 + t * 8;
            gload16(A + (size_t)(m0 + rb + srow) * DM + k0 + sc * 8, Ao[buf] + rb * 64);
        }
#pragma unroll
        for (int t = 0; t < 4; t++) {
            int rb = wave * 32 + t * 8;
            gload16(Bt + (size_t)(n0 + rb + srow) * DM + k0 + sc * 8, Bo[buf] + rb * 64);
        }
    };

    floatx4 zero = {0.f, 0.f, 0.f, 0.f};
    floatx4 acc[4][2];
#pragma unroll
    for (int i = 0; i < 4; i++)
#pragma unroll
        for (int j = 0; j < 2; j++) acc[i][j] = zero;

    stage(0, 0);
    for (int kt = 0; kt < DM / 64; kt++) {
        __syncthreads();
        if (kt + 1 < DM / 64) stage((kt + 1) & 1, (kt + 1) * 64);
        const bf16* As = Ao[kt & 1];
        const bf16* Bs = Bo[kt & 1];
#pragma unroll
        for (int ks = 0; ks < 2; ks++) {
            bf16x8_t af[4], bfr[2];
#pragma unroll
            for (int i = 0; i < 4; i++)
                af[i] = *(const bf16x8_t*)(As + (i * 16 + l15) * 64 + (((ks * 4 + quad) ^ h7) * 8));
#pragma unroll
            for (int j = 0; j < 2; j++)
                bfr[j] = *(const bf16x8_t*)(Bs + (nw + j * 16 + l15) * 64 + (((ks * 4 + quad) ^ h7) * 8));
#pragma unroll
            for (int i = 0; i < 4; i++)
#pragma unroll
                for (int j = 0; j < 2; j++)
                    acc[i][j] = __builtin_amdgcn_mfma_f32_16x16x32_bf16(af[i], bfr[j], acc[i][j], 0, 0, 0);
        }
    }
#pragma unroll
    for (int i = 0; i < 4; i++)
#pragma unroll
        for (int j = 0; j < 2; j++)
#pragma unroll
            for (int r = 0; r < 4; r++) {
                int m = m0 + i * 16 + quad * 4 + r;
                int n = n0 + nw + j * 16 + l15;
                out[(size_t)m * DM + n] = acc[i][j][r] + bo[n];
            }
}

// Flash attention (R3/R7's exact passing kernel): S^T orientation, kv-split waves,
// 4-buffer unroll-2. Block: 4 waves = 2 q-halves(64q) x 2 kv-halves(32kv).
// Grid 512 (32 bh x 16 qtiles of 128 q).
__global__ __launch_bounds__(256, 2) void flash_attn(
        const bf16* __restrict__ Q, const bf16* __restrict__ Kh,
        const bf16* __restrict__ Vt, bf16* __restrict__ Ob) {
    __shared__ __attribute__((aligned(16))) bf16 SMEM[4 * 8192];   // 4 bufs x (K 4096 | V 4096)
    const int tid = threadIdx.x;
    const int wave = tid >> 6, lane = tid & 63;
    const int l15 = lane & 15, quad = lane >> 4, h7 = l15 & 7;
    const int qh = wave >> 1, kvh = wave & 1;
    const int qt = blockIdx.x & 15, bh = blockIdx.x >> 4;
    const int q0 = qt * 128;
    const bf16* Kb = Kh + (size_t)bh * SEQ * DH;
    const bf16* Vb = Vt + (size_t)bh * DH * SEQ;

    // Q fragments: B-operand [n=q][k=d], 4 subtiles of 16 q each (64 q per wave)
    bf16x8_t aq[4][2];
#pragma unroll
    for (int sub = 0; sub < 4; sub++) {
        const bf16* qr = Q + ((size_t)bh * SEQ + q0 + qh * 64 + sub * 16 + l15) * DH;
        aq[sub][0] = *(const bf16x8_t*)(qr + quad * 8);
        aq[sub][1] = *(const bf16x8_t*)(qr + 32 + quad * 8);
    }

    const int srow = lane >> 3, sc = (lane & 7) ^ srow;
    auto stage = [&](int buf, int kv0) {
#pragma unroll
        for (int t = 0; t < 2; t++) {
            int rb = wave * 16 + t * 8;
            gload16(Kb + (size_t)(kv0 + rb + srow) * DH + sc * 8, SMEM + buf * 8192 + rb * 64);
            gload16(Vb + (size_t)(rb + srow) * SEQ + kv0 + sc * 8, SMEM + buf * 8192 + 4096 + rb * 64);
        }
    };

    floatx4 zero = {0.f, 0.f, 0.f, 0.f};
    floatx4 oacc[4][4];
    float l_run[4] = {0.f, 0.f, 0.f, 0.f};
#pragma unroll
    for (int sub = 0; sub < 4; sub++)
#pragma unroll
        for (int d = 0; d < 4; d++) oacc[sub][d] = zero;

    stage(0, 0);
    stage(1, 64);
    for (int seg = 0; seg < 16; seg++) {
        __syncthreads();
        if (seg < 15) {
            stage((2 * seg + 2) & 3, (2 * seg + 2) * 64);
            stage((2 * seg + 3) & 3, (2 * seg + 3) * 64);
        }
#pragma unroll
        for (int half = 0; half < 2; half++) {
            const bf16* Ks = SMEM + ((2 * seg + half) & 3) * 8192;
            const bf16* Vs = Ks + 4096;
            floatx4 st[4][2];
#pragma unroll
            for (int nsl = 0; nsl < 2; nsl++) {
                int row = (kvh * 2 + nsl) * 16 + l15;
                const bf16* kr = Ks + row * 64;
                bf16x8_t k0 = *(const bf16x8_t*)(kr + ((quad ^ h7) * 8));
                bf16x8_t k1 = *(const bf16x8_t*)(kr + (((4 + quad) ^ h7) * 8));
#pragma unroll
                for (int sub = 0; sub < 4; sub++) {
                    floatx4 a = zero;
                    a = __builtin_amdgcn_mfma_f32_16x16x32_bf16(k0, aq[sub][0], a, 0, 0, 0);
                    a = __builtin_amdgcn_mfma_f32_16x16x32_bf16(k1, aq[sub][1], a, 0, 0, 0);
                    st[sub][nsl] = a;
                }
            }
#pragma unroll
            for (int sub = 0; sub < 4; sub++) {
                float s = 0.f;
#pragma unroll
                for (int nsl = 0; nsl < 2; nsl++)
#pragma unroll
                    for (int r = 0; r < 4; r++) {
                        float p = __builtin_amdgcn_exp2f(st[sub][nsl][r]);
                        st[sub][nsl][r] = p;
                        s += p;
                    }
                l_run[sub] += s;
            }
#pragma unroll
            for (int cl = 0; cl < 2; cl++) {
                int c = kvh * 2 + cl;
                shortx4 ap[4];
#pragma unroll
                for (int sub = 0; sub < 4; sub++) ap[sub] = pack4(st[sub][cl]);
                int cc = 2 * c + (quad >> 1);
#pragma unroll
                for (int d = 0; d < 4; d++) {
                    const bf16* vr = Vs + (d * 16 + l15) * 64;
                    shortx4 bv = *(const shortx4*)(vr + ((cc ^ h7) * 8) + (quad & 1) * 4);
#pragma unroll
                    for (int sub = 0; sub < 4; sub++)
                        oacc[sub][d] = __builtin_amdgcn_mfma_f32_16x16x16bf16_1k(ap[sub], bv, oacc[sub][d], 0, 0, 0);
                }
            }
        }
    }

    // reduce l across quads (q = l15), then combine kv-halves via LDS blob
    float lf[4];
#pragma unroll
    for (int sub = 0; sub < 4; sub++) {
        float l = l_run[sub];
        l += __shfl_xor(l, 16, 64);
        l += __shfl_xor(l, 32, 64);
        lf[sub] = l;
    }
    __syncthreads();
    float* blob = (float*)SMEM + qh * (68 * 64);   // SoA [68][64] per q-half
    if (kvh == 1) {
#pragma unroll
        for (int sub = 0; sub < 4; sub++)
#pragma unroll
            for (int d = 0; d < 4; d++)
#pragma unroll
                for (int r = 0; r < 4; r++)
                    blob[((sub * 4 + d) * 4 + r) * 64 + lane] = oacc[sub][d][r];
#pragma unroll
        for (int sub = 0; sub < 4; sub++)
            blob[(64 + sub) * 64 + lane] = lf[sub];
    }
    __syncthreads();
    if (kvh == 0) {
#pragma unroll
        for (int sub = 0; sub < 4; sub++)
#pragma unroll
            for (int d = 0; d < 4; d++)
#pragma unroll
                for (int r = 0; r < 4; r++)
                    oacc[sub][d][r] += blob[((sub * 4 + d) * 4 + r) * 64 + lane];
#pragma unroll
        for (int sub = 0; sub < 4; sub++)
            lf[sub] += blob[(64 + sub) * 64 + lane];

        const int b = bh >> 3, h = bh & 7;
#pragma unroll
        for (int sub = 0; sub < 4; sub++) {
            float linv[4];
#pragma unroll
            for (int r = 0; r < 4; r++) linv[r] = 1.0f / __shfl(lf[sub], quad * 4 + r, 64);
#pragma unroll
            for (int d = 0; d < 4; d++)
#pragma unroll
                for (int r = 0; r < 4; r++) {
                    int s = q0 + qh * 64 + sub * 16 + quad * 4 + r;
                    Ob[((size_t)b * SEQ + s) * DM + h * DH + d * 16 + l15] = (bf16)(oacc[sub][d][r] * linv[r]);
                }
        }
    }
}

extern "C" void kernel_launch(void* const* d_in, const int* in_sizes, int n_in,
                              void* d_out, int out_size, void* d_ws, size_t ws_size,
                              hipStream_t stream) {
    const float* X  = (const float*)d_in[0];
    const float* Wq = (const float*)d_in[1];
    const float* Wk = (const float*)d_in[2];
    const float* Wv = (const float*)d_in[3];
    const float* Wo = (const float*)d_in[4];
    const float* bo = (const float*)d_in[5];
    float* out = (float*)d_out;

    char* ws = (char*)d_ws;
    bf16* Xb    = (bf16*)(ws + 0);
    bf16* Wqkvt = (bf16*)(ws + 8388608);
    bf16* Wot   = (bf16*)(ws + 9961472);
    bf16* Qh    = (bf16*)(ws + 10485760);
    bf16* Kh    = (bf16*)(ws + 18874368);
    bf16* Vt    = (bf16*)(ws + 27262976);
    bf16* Ob    = (bf16*)(ws + 35651584);

    prep<<<4096 + 256, 256, 0, stream>>>(X, Wq, Wk, Wv, Wo, Xb, Wqkvt, Wot);
    gemm_qkv<<<dim3(MTOT / 128, 1536 / 128), 256, 0, stream>>>(Xb, Wqkvt, Qh, Kh, Vt);
    flash_attn<<<NB * NH * (SEQ / 128), 256, 0, stream>>>(Qh, Kh, Vt, Ob);
    gemm_out<<<dim3(MTOT / 64, DM / 128), 256, 0, stream>>>(Ob, Wot, bo, out);
}